// Round 9
// baseline (301.200 us; speedup 1.0000x reference)
//
#include <hip/hip_runtime.h>

typedef _Float16 f16;
typedef _Float16 f16x8 __attribute__((ext_vector_type(8)));
typedef _Float16 f16x4 __attribute__((ext_vector_type(4)));
typedef float    f32x4 __attribute__((ext_vector_type(4)));

#define MFMA16(a,b,c) __builtin_amdgcn_mfma_f32_16x16x32_f16(a,b,c,0,0,0)

static constexpr float NEGV = -1e9f;
static constexpr float SC   = 0.05f;   // 1/SCALE = 1/20

// Fragment-major layouts (written by proj):
//  Q,K:  [bh][tile16 t][ds 0..5][slot 0..63][e 0..7]   slot=(g*16+c) <-> row=t*16+c, col=ds*32+g*8+e
//  V:    [bh][kb64][cid 0..23][slot][e]  cid=dt*2+ks  <-> d=dt*16+c,  k=kb64*64+ks*32+g*8+e
//  P:    [bh][poff(qt)+kc][slot][e]  A-frag: slot=(g*16+c) <-> q=qt*16+c, k=kc*32+g*8+e
//        triangular packed: kc = 0..qt>>1 ; 4160 chunks/bh

__device__ __forceinline__ int poff(int qt){
    int m = qt>>1;
    return qt + m*(m-1) + ((qt&1) ? m : 0);
}

__device__ __forceinline__ void gload16(const void* g, void* l){
    __builtin_amdgcn_global_load_lds(
        (const __attribute__((address_space(1))) void*)g,
        (__attribute__((address_space(3))) void*)l, 16, 0, 0);
}

// ---------------- f32 -> f16 convert ----------------
__global__ __launch_bounds__(256) void cvt_kernel(const float* __restrict__ in,
                                                  f16* __restrict__ out, int n){
    int i = (blockIdx.x*256 + threadIdx.x)*4;
    if (i < n){
        float4 v = *reinterpret_cast<const float4*>(in + i);
        f16x4 o = { (f16)v.x, (f16)v.y, (f16)v.z, (f16)v.w };
        *reinterpret_cast<f16x4*>(out + i) = o;
    }
}

// fused convert of the 3 weight matrices
__global__ __launch_bounds__(256) void cvtw_kernel(const float* __restrict__ a,
                                                   const float* __restrict__ b,
                                                   const float* __restrict__ c,
                                                   f16* __restrict__ out){
    int idx = blockIdx.x*256 + threadIdx.x;            // 442368 threads
    int which = idx / 147456;                          // 589824/4 per matrix
    int r = idx - which*147456;
    const float* src = (which==0) ? a : (which==1 ? b : c);
    int i = r*4;
    float4 v = *reinterpret_cast<const float4*>(src + i);
    f16x4 o = { (f16)v.x, (f16)v.y, (f16)v.z, (f16)v.w };
    *reinterpret_cast<f16x4*>(out + (size_t)which*589824 + i) = o;
}

// ---------------- zero-init f32 buffer ----------------
__global__ __launch_bounds__(256) void zero_kernel(float* __restrict__ p, int n){
    int i = (blockIdx.x*256 + threadIdx.x)*4;
    if (i < n){
        float4 z = {0.f,0.f,0.f,0.f};
        *reinterpret_cast<float4*>(p + i) = z;
    }
}

// ---------------- QKV projection ----------------
__global__ __launch_bounds__(256) void proj_kernel(
    const f16* __restrict__ xb, const f16* __restrict__ Wb,
    const float* __restrict__ bq, const float* __restrict__ bk, const float* __restrict__ bv,
    f16* __restrict__ Qb, f16* __restrict__ Kb, f16* __restrict__ Vt)
{
    __shared__ f16 As[128*32];
    __shared__ f16 Bs[128*32];
    const int z = blockIdx.z;
    const f16*   Wz   = Wb + (size_t)z*768*768;
    const float* bias = (z==0) ? bq : (z==1 ? bk : bv);
    f16*         out  = (z==0) ? Qb : (z==1 ? Kb : Vt);
    const int row0 = blockIdx.y*128, n0 = blockIdx.x*128;
    const int tid = threadIdx.x, w = tid>>6, l = tid&63;
    const int wm = w>>1, wn = w&1, c = l&15, g = l>>4;
    f32x4 zero = {0.f,0.f,0.f,0.f};
    f32x4 acc[4][4];
    for (int i=0;i<4;i++) for (int j=0;j<4;j++) acc[i][j] = zero;

    const f16* ag = xb + (size_t)(row0 + w*32 + (l>>2))*768 + (l&3)*8;
    const f16* bg = Wz + (size_t)(n0   + w*32 + (l>>2))*768 + (l&3)*8;
    f16* asd = As + w*1024;
    f16* bsd = Bs + w*1024;

    for (int k0 = 0; k0 < 768; k0 += 32){
        __syncthreads();
        gload16(ag + k0,          asd      );
        gload16(ag + k0 + 16*768, asd + 512);
        gload16(bg + k0,          bsd      );
        gload16(bg + k0 + 16*768, bsd + 512);
        __syncthreads();
        f16x8 af[4], bf[4];
        for (int mt=0; mt<4; mt++)
            af[mt] = *reinterpret_cast<const f16x8*>(As + (wm*64 + mt*16 + c)*32 + g*8);
        for (int nt=0; nt<4; nt++)
            bf[nt] = *reinterpret_cast<const f16x8*>(Bs + (wn*64 + nt*16 + c)*32 + g*8);
        for (int mt=0; mt<4; mt++)
            for (int nt=0; nt<4; nt++)
                acc[mt][nt] = MFMA16(af[mt], bf[nt], acc[mt][nt]);
    }

    for (int nt=0; nt<4; nt++){
        int nb = n0 + wn*64 + nt*16;
        int h  = nb/192;
        int d  = (nb - h*192) + c;
        float bv_ = bias[nb + c];
        for (int mt=0; mt<4; mt++){
            int mb = row0 + wm*64 + mt*16 + g*4;
            int bi = mb>>11, s0 = mb&2047;
            int bh = bi*4 + h;
            if (z < 2){
                int ds = d>>5, gg = (d>>3)&3, e = d&7;
                for (int r=0;r<4;r++){
                    int s = s0 + r;
                    out[ ((size_t)(bh*128 + (s>>4))*6 + ds)*512 + ((gg*16) + (s&15))*8 + e ]
                        = (f16)(acc[mt][nt][r] + bv_);
                }
            } else {
                int dt = d>>4, cV = d&15;
                int kb64 = s0>>6, ks = (s0>>5)&1, gk = (s0>>3)&3, e0 = s0&7;
                f16x4 pk = { (f16)(acc[mt][nt][0] + bv_), (f16)(acc[mt][nt][1] + bv_),
                             (f16)(acc[mt][nt][2] + bv_), (f16)(acc[mt][nt][3] + bv_) };
                *reinterpret_cast<f16x4*>(
                    &out[ ((size_t)(bh*32 + kb64)*24 + dt*2 + ks)*512 + (gk*16 + cV)*8 + e0 ]) = pk;
            }
        }
    }
}

// pass 1: P = exp(S*SC) (masked, causal-zeroed), stored A-frag packed; L[k] += col sums.
// grid (qb=16, ch=4, bh=16), 512 thr. k-step 64, double-buffered.
__global__ __launch_bounds__(512,4) void qkexp_kernel(
    const f16* __restrict__ Qb, const f16* __restrict__ Kb,
    const unsigned char* __restrict__ am,
    float* __restrict__ L, f16* __restrict__ Pg)
{
    __shared__ f16 Ks[2][24*512];    // 2 x 24KB (64-k K tile)
    __shared__ f16 Pl[8][16*32];
    const int bh = blockIdx.z, b = bh>>2;
    const int qb = blockIdx.x;
    const int ch = blockIdx.y;
    if (qb < 4*ch) return;
    const int tid = threadIdx.x, w = tid>>6, l = tid&63;
    const int c = l&15, g = l>>4;
    const int qt = qb*8 + w, qw = qt*16;
    const f16* Kfm = Kb + (size_t)bh*128*6*512;
    char* Pb = (char*)(&Pl[w][0]);
    f16* pw = Pg + ((size_t)bh*4160 + poff(qt))*512 + l*8;
    float* Lb = L + bh*2048;

    f16x8 qf[6];
    {
        const f16* qbase = Qb + ((size_t)(bh*128 + qt)*6)*512 + l*8;
        for (int ds=0; ds<6; ds++) qf[ds] = *reinterpret_cast<const f16x8*>(qbase + ds*512);
    }
    bool pm[4];
    for (int r=0;r<4;r++) pm[r] = am[b*2048 + qw + g*4 + r] != 0;

    f32x4 zero = {0.f,0.f,0.f,0.f};
    const int k00  = ch*512;
    const int kend = min(ch*512 + 512, qb*128 + 128);
    const int nt   = (kend - k00) >> 6;
    const int cid  = w*3;   // all 8 waves stage 3 of 24 chunks

    auto stage = [&](int buf, int k0){
        for (int i=0;i<3;i++){
            int ci = cid + i;
            int tl = ci/6, ds = ci - tl*6;
            gload16(Kfm + ((size_t)((k0>>4) + tl)*6 + ds)*512 + l*8, &Ks[buf][ci*512]);
        }
    };

    stage(0, k00);
    __syncthreads();
    for (int it=0; it<nt; it++){
        int cur = it&1;
        int k0  = k00 + it*64;
        if (it+1 < nt) stage(cur^1, k0 + 64);

        for (int half=0; half<2; half++){
            int kh = k0 + half*32;
            if (kh <= qw + 15){
                float cs[2];
                for (int kt2=0; kt2<2; kt2++){
                    int ktile = half*2 + kt2;
                    int kk = k0 + ktile*16;
                    f32x4 sacc = zero;
                    for (int ds=0; ds<6; ds++){
                        f16x8 kfr = *reinterpret_cast<const f16x8*>(&Ks[cur][(ktile*6+ds)*512 + l*8]);
                        sacc = MFMA16(qf[ds], kfr, sacc);
                    }
                    float csl = 0.f;
                    for (int r=0;r<4;r++){
                        int q = qw + g*4 + r;
                        float v = sacc[r]*SC;
                        if (pm[r]) v = NEGV;
                        float p = __expf(v);
                        if (kk + c > q) p = 0.f;
                        csl += p;
                        int row = g*4 + r;
                        int byo = (row*64 + (kt2*16 + c)*2) ^ ((row&3)<<4);
                        *reinterpret_cast<f16*>(Pb + byo) = (f16)p;
                    }
                    csl += __shfl_xor(csl, 16);
                    csl += __shfl_xor(csl, 32);
                    cs[kt2] = csl;
                }
                {
                    int byo = (c*64 + g*16) ^ ((c&3)<<4);
                    f16x8 pa = *reinterpret_cast<const f16x8*>(Pb + byo);
                    *reinterpret_cast<f16x8*>(pw + (size_t)(kh>>5)*512) = pa;
                }
                if (l < 32){
                    float csv = (l < 16) ? cs[0] : cs[1];
                    int kcol = kh + ((l < 16) ? 0 : 16) + (l & 15);
                    atomicAdd(&Lb[kcol], csv);
                }
            }
        }
        __syncthreads();
    }
}

// scale V in place: V'[k,:] = V[k,:] / L[k]
__global__ __launch_bounds__(256) void scalev_kernel(f16* __restrict__ V, const float* __restrict__ L){
    int idx = blockIdx.x*256 + threadIdx.x;
    size_t base = (size_t)idx * 8;
    int bh = idx / 49152;
    int rem = idx - bh*49152;
    int chunk = rem >> 6;
    int sl = rem & 63;
    int kb64 = chunk/24, cr = chunk - kb64*24;
    int ks = cr & 1;
    int gk = sl >> 4;
    int k0 = kb64*64 + ks*32 + gk*8;
    const float* Lb = L + bh*2048 + k0;
    f16x8 v = *reinterpret_cast<f16x8*>(V + base);
    f16x8 o;
    for (int e=0;e<8;e++){
        float Lv = fmaxf(Lb[e], 1e-30f);
        o[e] = (f16)((float)v[e] / Lv);
    }
    *reinterpret_cast<f16x8*>(V + base) = o;
}

// pass 2: x1 += P @ V'  (k-chunked, atomic f32 accumulation; P reg double-buffered)
// grid (qb=16, ch=4, bh=16), 512 thr.
__global__ __launch_bounds__(512,4) void pv_kernel(
    const f16* __restrict__ Pg, const f16* __restrict__ Vt,
    float* __restrict__ x1)
{
    __shared__ f16 Vs[2][12*512];    // 2 x 12KB (32-k V' tile)
    const int bh = blockIdx.z, b = bh>>2, h = bh&3;
    const int qb = blockIdx.x;
    const int ch = blockIdx.y;
    if (qb < 4*ch) return;
    const int tid = threadIdx.x, w = tid>>6, l = tid&63;
    const int c = l&15, g = l>>4;
    const int qt = qb*8 + w, qw = qt*16;
    const f16* Vfm = Vt + (size_t)bh*32*24*512;
    const f16* pp  = Pg + ((size_t)bh*4160 + poff(qt))*512 + l*8;

    f32x4 zero = {0.f,0.f,0.f,0.f};
    f32x4 acc[12];
    for (int i=0;i<12;i++) acc[i] = zero;

    const int k00  = ch*512;
    const int kend = min(ch*512 + 512, qb*128 + 128);
    const int nt   = (kend - k00) >> 5;
    const int cid  = w*3;            // waves 0..3 stage the 12 V chunks

    auto stage = [&](int buf, int k0){
        for (int i=0;i<3;i++){
            int ci = cid + i;
            if (ci < 12)
                gload16(Vfm + ((size_t)(k0>>6)*24 + ci*2 + ((k0>>5)&1))*512 + l*8, &Vs[buf][ci*512]);
        }
    };

    stage(0, k00);
    // prefetch first P fragment (k00 <= qw+15 always holds for valid blocks/waves)
    f16x8 pa_cur = *reinterpret_cast<const f16x8*>(pp + (size_t)(k00>>5)*512);
    __syncthreads();
    for (int it=0; it<nt; it++){
        int cur = it&1;
        int k0  = k00 + it*32;
        if (it+1 < nt) stage(cur^1, k0 + 32);

        f16x8 pa_next = pa_cur;
        bool actn = (it+1 < nt) && (k0 + 32 <= qw + 15);
        if (actn) pa_next = *reinterpret_cast<const f16x8*>(pp + (size_t)((k0+32)>>5)*512);

        if (k0 <= qw + 15){
            for (int dt=0; dt<12; dt++){
                f16x8 vb = *reinterpret_cast<const f16x8*>(&Vs[cur][dt*512 + l*8]);
                acc[dt] = MFMA16(pa_cur, vb, acc[dt]);
            }
        }
        __syncthreads();
        pa_cur = pa_next;
    }
    for (int dt=0; dt<12; dt++){
        int d = h*192 + dt*16 + c;
        for (int r=0;r<4;r++){
            int q = qw + g*4 + r;
            atomicAdd(&x1[(size_t)(b*2048 + q)*768 + d], acc[dt][r]);
        }
    }
}

// ---------------- residual + layernorm ----------------
__global__ __launch_bounds__(256) void ln_kernel(
    const float* __restrict__ x, const float* __restrict__ x1,
    const float* __restrict__ gamma, const float* __restrict__ beta,
    float* __restrict__ out)
{
    const int r = blockIdx.x, t = threadIdx.x;
    const float* xr = x  + (size_t)r*768;
    const float* yr = x1 + (size_t)r*768;
    float v[3]; float s1 = 0.f, s2 = 0.f;
    for (int i=0;i<3;i++){ int j = t + i*256; float y = xr[j] + yr[j]; v[i]=y; s1+=y; s2+=y*y; }
    for (int o=32;o>=1;o>>=1){ s1 += __shfl_xor(s1,o); s2 += __shfl_xor(s2,o); }
    __shared__ float a1[4], a2[4];
    if ((t&63)==0){ a1[t>>6]=s1; a2[t>>6]=s2; }
    __syncthreads();
    s1 = a1[0]+a1[1]+a1[2]+a1[3];
    s2 = a2[0]+a2[1]+a2[2]+a2[3];
    float mu  = s1*(1.f/768.f);
    float var = s2*(1.f/768.f) - mu*mu;
    float rs  = rsqrtf(var + 1e-5f);
    for (int i=0;i<3;i++){
        int j = t + i*256;
        out[(size_t)r*768 + j] = (v[i]-mu)*rs*gamma[j] + beta[j];
    }
}

extern "C" void kernel_launch(void* const* d_in, const int* in_sizes, int n_in,
                              void* d_out, int out_size, void* d_ws, size_t ws_size,
                              hipStream_t stream)
{
    const float* x     = (const float*)d_in[0];
    const unsigned char* am = (const unsigned char*)d_in[1];
    const float* Wq    = (const float*)d_in[2];
    const float* bq    = (const float*)d_in[3];
    const float* Wk    = (const float*)d_in[4];
    const float* bk    = (const float*)d_in[5];
    const float* Wv    = (const float*)d_in[6];
    const float* bv    = (const float*)d_in[7];
    const float* gamma = (const float*)d_in[8];
    const float* beta  = (const float*)d_in[9];
    float* out = (float*)d_out;

    f16* xb  = (f16*)d_ws;
    f16* Wb  = xb + (size_t)8192*768;
    f16* Qb  = Wb + (size_t)3*768*768;
    f16* Kb  = Qb + (size_t)16*2048*192;
    f16* Vt  = Kb + (size_t)16*2048*192;
    f16* Pg  = Vt + (size_t)16*2048*192;       // 68,157,440 B (triangular-packed P)
    float* L  = (float*)xb;                    // aliases xb (dead after proj)
    float* x1 = (float*)Qb;                    // aliases Qb+Kb (dead after qkexp)

    cvt_kernel<<<6144, 256, 0, stream>>>(x,  xb, 8192*768);
    cvtw_kernel<<<1728, 256, 0, stream>>>(Wq, Wk, Wv, Wb);
    proj_kernel<<<dim3(6,64,3), 256, 0, stream>>>(xb, Wb, bq, bk, bv, Qb, Kb, Vt);
    zero_kernel<<<32, 256, 0, stream>>>(L, 16*2048);
    qkexp_kernel<<<dim3(16,4,16), 512, 0, stream>>>(Qb, Kb, am, L, Pg);
    zero_kernel<<<6144, 256, 0, stream>>>(x1, 8192*768);
    scalev_kernel<<<3072, 256, 0, stream>>>(Vt, L);
    pv_kernel<<<dim3(16,4,16), 512, 0, stream>>>(Pg, Vt, x1);
    ln_kernel<<<8192, 256, 0, stream>>>(x, x1, gamma, beta, out);
}

// Round 11
// 282.399 us; speedup vs baseline: 1.0666x; 1.0666x over previous
//
#include <hip/hip_runtime.h>

typedef _Float16 f16;
typedef _Float16 f16x8 __attribute__((ext_vector_type(8)));
typedef _Float16 f16x4 __attribute__((ext_vector_type(4)));
typedef float    f32x4 __attribute__((ext_vector_type(4)));

#define MFMA16(a,b,c) __builtin_amdgcn_mfma_f32_16x16x32_f16(a,b,c,0,0,0)

static constexpr float NEGV = -1e9f;
static constexpr float SC   = 0.05f;   // 1/SCALE = 1/20

// Fragment-major layouts (written by proj):
//  Q,K:  [bh][tile16 t][ds 0..5][slot 0..63][e 0..7]   slot=(g*16+c) <-> row=t*16+c, col=ds*32+g*8+e
//  V:    [bh][kb64][cid 0..23][slot][e]  cid=dt*2+ks  <-> d=dt*16+c,  k=kb64*64+ks*32+g*8+e
//  P:    [bh][poff(qt)+kc][slot][e]  A-frag: slot=(g*16+c) <-> q=qt*16+c, k=kc*32+g*8+e
//        triangular packed: kc = 0..qt>>1 ; 4160 chunks/bh

__device__ __forceinline__ int poff(int qt){
    int m = qt>>1;
    return qt + m*(m-1) + ((qt&1) ? m : 0);
}

__device__ __forceinline__ void gload16(const void* g, void* l){
    __builtin_amdgcn_global_load_lds(
        (const __attribute__((address_space(1))) void*)g,
        (__attribute__((address_space(3))) void*)l, 16, 0, 0);
}

// ---------------- f32 -> f16 convert ----------------
__global__ __launch_bounds__(256) void cvt_kernel(const float* __restrict__ in,
                                                  f16* __restrict__ out, int n){
    int i = (blockIdx.x*256 + threadIdx.x)*4;
    if (i < n){
        float4 v = *reinterpret_cast<const float4*>(in + i);
        f16x4 o = { (f16)v.x, (f16)v.y, (f16)v.z, (f16)v.w };
        *reinterpret_cast<f16x4*>(out + i) = o;
    }
}

// fused convert of the 3 weight matrices
__global__ __launch_bounds__(256) void cvtw_kernel(const float* __restrict__ a,
                                                   const float* __restrict__ b,
                                                   const float* __restrict__ c,
                                                   f16* __restrict__ out){
    int idx = blockIdx.x*256 + threadIdx.x;
    int which = idx / 147456;
    int r = idx - which*147456;
    const float* src = (which==0) ? a : (which==1 ? b : c);
    int i = r*4;
    float4 v = *reinterpret_cast<const float4*>(src + i);
    f16x4 o = { (f16)v.x, (f16)v.y, (f16)v.z, (f16)v.w };
    *reinterpret_cast<f16x4*>(out + (size_t)which*589824 + i) = o;
}

// ---------------- zero-init f32 buffer ----------------
__global__ __launch_bounds__(256) void zero_kernel(float* __restrict__ p, int n){
    int i = (blockIdx.x*256 + threadIdx.x)*4;
    if (i < n){
        float4 z = {0.f,0.f,0.f,0.f};
        *reinterpret_cast<float4*>(p + i) = z;
    }
}

// ---------------- QKV projection (2-phase double-buffered staging) ----------------
__global__ __launch_bounds__(256) void proj_kernel(
    const f16* __restrict__ xb, const f16* __restrict__ Wb,
    const float* __restrict__ bq, const float* __restrict__ bk, const float* __restrict__ bv,
    f16* __restrict__ Qb, f16* __restrict__ Kb, f16* __restrict__ Vt)
{
    __shared__ f16 As[2][128*32];
    __shared__ f16 Bs[2][128*32];
    const int z = blockIdx.z;
    const f16*   Wz   = Wb + (size_t)z*768*768;
    const float* bias = (z==0) ? bq : (z==1 ? bk : bv);
    f16*         out  = (z==0) ? Qb : (z==1 ? Kb : Vt);
    const int row0 = blockIdx.y*128, n0 = blockIdx.x*128;
    const int tid = threadIdx.x, w = tid>>6, l = tid&63;
    const int wm = w>>1, wn = w&1, c = l&15, g = l>>4;
    f32x4 zero = {0.f,0.f,0.f,0.f};
    f32x4 acc[4][4];
    for (int i=0;i<4;i++) for (int j=0;j<4;j++) acc[i][j] = zero;

    const f16* ag = xb + (size_t)(row0 + w*32 + (l>>2))*768 + (l&3)*8;
    const f16* bg = Wz + (size_t)(n0   + w*32 + (l>>2))*768 + (l&3)*8;

    auto stage = [&](int buf, int k0){
        gload16(ag + k0,          &As[buf][w*1024      ]);
        gload16(ag + k0 + 16*768, &As[buf][w*1024 + 512]);
        gload16(bg + k0,          &Bs[buf][w*1024      ]);
        gload16(bg + k0 + 16*768, &Bs[buf][w*1024 + 512]);
    };

    stage(0, 0);
    __syncthreads();
    for (int it=0; it<24; it++){
        int cur = it&1;
        if (it < 23) stage(cur^1, (it+1)*32);
        f16x8 af[4], bf[4];
        for (int mt=0; mt<4; mt++)
            af[mt] = *reinterpret_cast<const f16x8*>(&As[cur][(wm*64 + mt*16 + c)*32 + g*8]);
        for (int nt=0; nt<4; nt++)
            bf[nt] = *reinterpret_cast<const f16x8*>(&Bs[cur][(wn*64 + nt*16 + c)*32 + g*8]);
        for (int mt=0; mt<4; mt++)
            for (int nt=0; nt<4; nt++)
                acc[mt][nt] = MFMA16(af[mt], bf[nt], acc[mt][nt]);
        __syncthreads();
    }

    for (int nt=0; nt<4; nt++){
        int nb = n0 + wn*64 + nt*16;
        int h  = nb/192;
        int d  = (nb - h*192) + c;
        float bv_ = bias[nb + c];
        for (int mt=0; mt<4; mt++){
            int mb = row0 + wm*64 + mt*16 + g*4;
            int bi = mb>>11, s0 = mb&2047;
            int bh = bi*4 + h;
            if (z < 2){
                int ds = d>>5, gg = (d>>3)&3, e = d&7;
                for (int r=0;r<4;r++){
                    int s = s0 + r;
                    out[ ((size_t)(bh*128 + (s>>4))*6 + ds)*512 + ((gg*16) + (s&15))*8 + e ]
                        = (f16)(acc[mt][nt][r] + bv_);
                }
            } else {
                int dt = d>>4, cV = d&15;
                int kb64 = s0>>6, ks = (s0>>5)&1, gk = (s0>>3)&3, e0 = s0&7;
                f16x4 pk = { (f16)(acc[mt][nt][0] + bv_), (f16)(acc[mt][nt][1] + bv_),
                             (f16)(acc[mt][nt][2] + bv_), (f16)(acc[mt][nt][3] + bv_) };
                *reinterpret_cast<f16x4*>(
                    &out[ ((size_t)(bh*32 + kb64)*24 + dt*2 + ks)*512 + (gk*16 + cV)*8 + e0 ]) = pk;
            }
        }
    }
}

// pass 1: P = exp(S*SC) (masked, causal-zeroed), stored A-frag packed; L[k] += col sums.
// grid (qb=16, ch=4, bh=16), 512 thr. k-step 64, double-buffered.
__global__ __launch_bounds__(512,4) void qkexp_kernel(
    const f16* __restrict__ Qb, const f16* __restrict__ Kb,
    const unsigned char* __restrict__ am,
    float* __restrict__ L, f16* __restrict__ Pg)
{
    __shared__ f16 Ks[2][24*512];
    __shared__ f16 Pl[8][16*32];
    const int bh = blockIdx.z, b = bh>>2;
    const int qb = blockIdx.x;
    const int ch = blockIdx.y;
    if (qb < 4*ch) return;
    const int tid = threadIdx.x, w = tid>>6, l = tid&63;
    const int c = l&15, g = l>>4;
    const int qt = qb*8 + w, qw = qt*16;
    const f16* Kfm = Kb + (size_t)bh*128*6*512;
    char* Pb = (char*)(&Pl[w][0]);
    f16* pw = Pg + ((size_t)bh*4160 + poff(qt))*512 + l*8;
    float* Lb = L + bh*2048;

    f16x8 qf[6];
    {
        const f16* qbase = Qb + ((size_t)(bh*128 + qt)*6)*512 + l*8;
        for (int ds=0; ds<6; ds++) qf[ds] = *reinterpret_cast<const f16x8*>(qbase + ds*512);
    }
    bool pm[4];
    for (int r=0;r<4;r++) pm[r] = am[b*2048 + qw + g*4 + r] != 0;

    f32x4 zero = {0.f,0.f,0.f,0.f};
    const int k00  = ch*512;
    const int kend = min(ch*512 + 512, qb*128 + 128);
    const int nt   = (kend - k00) >> 6;
    const int cid  = w*3;

    auto stage = [&](int buf, int k0){
        for (int i=0;i<3;i++){
            int ci = cid + i;
            int tl = ci/6, ds = ci - tl*6;
            gload16(Kfm + ((size_t)((k0>>4) + tl)*6 + ds)*512 + l*8, &Ks[buf][ci*512]);
        }
    };

    stage(0, k00);
    __syncthreads();
    for (int it=0; it<nt; it++){
        int cur = it&1;
        int k0  = k00 + it*64;
        if (it+1 < nt) stage(cur^1, k0 + 64);

        for (int half=0; half<2; half++){
            int kh = k0 + half*32;
            if (kh <= qw + 15){
                float cs[2];
                for (int kt2=0; kt2<2; kt2++){
                    int ktile = half*2 + kt2;
                    int kk = k0 + ktile*16;
                    f32x4 sacc = zero;
                    for (int ds=0; ds<6; ds++){
                        f16x8 kfr = *reinterpret_cast<const f16x8*>(&Ks[cur][(ktile*6+ds)*512 + l*8]);
                        sacc = MFMA16(qf[ds], kfr, sacc);
                    }
                    float csl = 0.f;
                    for (int r=0;r<4;r++){
                        int q = qw + g*4 + r;
                        float v = sacc[r]*SC;
                        if (pm[r]) v = NEGV;
                        float p = __expf(v);
                        if (kk + c > q) p = 0.f;
                        csl += p;
                        int row = g*4 + r;
                        int byo = (row*64 + (kt2*16 + c)*2) ^ ((row&3)<<4);
                        *reinterpret_cast<f16*>(Pb + byo) = (f16)p;
                    }
                    csl += __shfl_xor(csl, 16);
                    csl += __shfl_xor(csl, 32);
                    cs[kt2] = csl;
                }
                {
                    int byo = (c*64 + g*16) ^ ((c&3)<<4);
                    f16x8 pa = *reinterpret_cast<const f16x8*>(Pb + byo);
                    *reinterpret_cast<f16x8*>(pw + (size_t)(kh>>5)*512) = pa;
                }
                if (l < 32){
                    float csv = (l < 16) ? cs[0] : cs[1];
                    int kcol = kh + ((l < 16) ? 0 : 16) + (l & 15);
                    atomicAdd(&Lb[kcol], csv);
                }
            }
        }
        __syncthreads();
    }
}

// scale V in place: V'[k,:] = V[k,:] / L[k]
__global__ __launch_bounds__(256) void scalev_kernel(f16* __restrict__ V, const float* __restrict__ L){
    int idx = blockIdx.x*256 + threadIdx.x;
    size_t base = (size_t)idx * 8;
    int bh = idx / 49152;
    int rem = idx - bh*49152;
    int chunk = rem >> 6;
    int sl = rem & 63;
    int kb64 = chunk/24, cr = chunk - kb64*24;
    int ks = cr & 1;
    int gk = sl >> 4;
    int k0 = kb64*64 + ks*32 + gk*8;
    const float* Lb = L + bh*2048 + k0;
    f16x8 v = *reinterpret_cast<f16x8*>(V + base);
    f16x8 o;
    for (int e=0;e<8;e++){
        float Lv = fmaxf(Lb[e], 1e-30f);
        o[e] = (f16)((float)v[e] / Lv);
    }
    *reinterpret_cast<f16x8*>(V + base) = o;
}

// pass 2: x1 = P @ V'. Barrier-free, LDS-free: per-wave task (qt, d-half, bh),
// pair-balanced qt (j <-> 127-j), direct coalesced global reads (P streams, V' L2-hot),
// plain f32 stores (each output written once). 4096 waves.
__global__ __launch_bounds__(512) void pv_kernel(
    const f16* __restrict__ Pg, const f16* __restrict__ Vt,
    float* __restrict__ x1)
{
    const int t  = blockIdx.x*8 + (threadIdx.x>>6);
    const int l  = threadIdx.x&63, c = l&15, g = l>>4;
    const int bh = t >> 8;
    const int r8 = t & 255;
    const int dh = r8 & 1;                 // d-half: dt = dh*6 + 0..5
    const int j  = r8 >> 1;
    const int qt = (j&1) ? (127 - (j>>1)) : (j>>1);
    const int b = bh>>2, h = bh&3;
    const int qw = qt*16;
    const f16* Vfm = Vt + (size_t)bh*32*24*512;
    const f16* pp  = Pg + ((size_t)bh*4160 + poff(qt))*512 + l*8;
    const int nc = (qt>>1) + 1;            // 32-wide k-chunks

    f32x4 zero = {0.f,0.f,0.f,0.f};
    f32x4 acc[6];
    for (int i=0;i<6;i++) acc[i] = zero;

    int kc = 0;
    for (; kc+1 < nc; kc += 2){
        // kc even: kc,kc+1 share kb64 = kc>>1 with ks=0,1
        const f16* pap = pp + (size_t)kc*512;
        f16x8 paA = *reinterpret_cast<const f16x8*>(pap);
        f16x8 paB = *reinterpret_cast<const f16x8*>(pap + 512);
        const f16* vb = Vfm + ((size_t)(kc>>1)*24 + dh*12)*512 + l*8;
        f16x8 vA[6], vB[6];
        #pragma unroll
        for (int d2=0; d2<6; d2++){
            vA[d2] = *reinterpret_cast<const f16x8*>(vb + d2*1024);
            vB[d2] = *reinterpret_cast<const f16x8*>(vb + d2*1024 + 512);
        }
        #pragma unroll
        for (int d2=0; d2<6; d2++) acc[d2] = MFMA16(paA, vA[d2], acc[d2]);
        #pragma unroll
        for (int d2=0; d2<6; d2++) acc[d2] = MFMA16(paB, vB[d2], acc[d2]);
    }
    if (kc < nc){
        f16x8 paA = *reinterpret_cast<const f16x8*>(pp + (size_t)kc*512);
        const f16* vb = Vfm + ((size_t)(kc>>1)*24 + dh*12)*512 + l*8;
        #pragma unroll
        for (int d2=0; d2<6; d2++){
            f16x8 vA = *reinterpret_cast<const f16x8*>(vb + d2*1024);
            acc[d2] = MFMA16(paA, vA, acc[d2]);
        }
    }

    for (int d2=0; d2<6; d2++){
        int d = h*192 + (dh*6 + d2)*16 + c;
        for (int r=0;r<4;r++){
            int q = qw + g*4 + r;
            x1[(size_t)(b*2048 + q)*768 + d] = acc[d2][r];
        }
    }
}

// ---------------- residual + layernorm ----------------
__global__ __launch_bounds__(256) void ln_kernel(
    const float* __restrict__ x, const float* __restrict__ x1,
    const float* __restrict__ gamma, const float* __restrict__ beta,
    float* __restrict__ out)
{
    const int r = blockIdx.x, t = threadIdx.x;
    const float* xr = x  + (size_t)r*768;
    const float* yr = x1 + (size_t)r*768;
    float v[3]; float s1 = 0.f, s2 = 0.f;
    for (int i=0;i<3;i++){ int j = t + i*256; float y = xr[j] + yr[j]; v[i]=y; s1+=y; s2+=y*y; }
    for (int o=32;o>=1;o>>=1){ s1 += __shfl_xor(s1,o); s2 += __shfl_xor(s2,o); }
    __shared__ float a1[4], a2[4];
    if ((t&63)==0){ a1[t>>6]=s1; a2[t>>6]=s2; }
    __syncthreads();
    s1 = a1[0]+a1[1]+a1[2]+a1[3];
    s2 = a2[0]+a2[1]+a2[2]+a2[3];
    float mu  = s1*(1.f/768.f);
    float var = s2*(1.f/768.f) - mu*mu;
    float rs  = rsqrtf(var + 1e-5f);
    for (int i=0;i<3;i++){
        int j = t + i*256;
        out[(size_t)r*768 + j] = (v[i]-mu)*rs*gamma[j] + beta[j];
    }
}

extern "C" void kernel_launch(void* const* d_in, const int* in_sizes, int n_in,
                              void* d_out, int out_size, void* d_ws, size_t ws_size,
                              hipStream_t stream)
{
    const float* x     = (const float*)d_in[0];
    const unsigned char* am = (const unsigned char*)d_in[1];
    const float* Wq    = (const float*)d_in[2];
    const float* bq    = (const float*)d_in[3];
    const float* Wk    = (const float*)d_in[4];
    const float* bk    = (const float*)d_in[5];
    const float* Wv    = (const float*)d_in[6];
    const float* bv    = (const float*)d_in[7];
    const float* gamma = (const float*)d_in[8];
    const float* beta  = (const float*)d_in[9];
    float* out = (float*)d_out;

    f16* xb  = (f16*)d_ws;
    f16* Wb  = xb + (size_t)8192*768;
    f16* Qb  = Wb + (size_t)3*768*768;
    f16* Kb  = Qb + (size_t)16*2048*192;
    f16* Vt  = Kb + (size_t)16*2048*192;
    f16* Pg  = Vt + (size_t)16*2048*192;       // triangular-packed P (68 MB)
    float* L  = (float*)xb;                    // aliases xb (dead after proj)
    float* x1 = (float*)Qb;                    // aliases Qb+Kb (dead after qkexp)

    cvt_kernel<<<6144, 256, 0, stream>>>(x,  xb, 8192*768);
    cvtw_kernel<<<1728, 256, 0, stream>>>(Wq, Wk, Wv, Wb);
    proj_kernel<<<dim3(6,64,3), 256, 0, stream>>>(xb, Wb, bq, bk, bv, Qb, Kb, Vt);
    zero_kernel<<<32, 256, 0, stream>>>(L, 16*2048);
    qkexp_kernel<<<dim3(16,4,16), 512, 0, stream>>>(Qb, Kb, am, L, Pg);
    scalev_kernel<<<3072, 256, 0, stream>>>(Vt, L);
    pv_kernel<<<512, 512, 0, stream>>>(Pg, Vt, x1);
    ln_kernel<<<8192, 256, 0, stream>>>(x, x1, gamma, beta, out);
}

// Round 12
// 271.377 us; speedup vs baseline: 1.1099x; 1.0406x over previous
//
#include <hip/hip_runtime.h>

typedef _Float16 f16;
typedef _Float16 f16x8 __attribute__((ext_vector_type(8)));
typedef _Float16 f16x4 __attribute__((ext_vector_type(4)));
typedef float    f32x4 __attribute__((ext_vector_type(4)));

#define MFMA16(a,b,c) __builtin_amdgcn_mfma_f32_16x16x32_f16(a,b,c,0,0,0)

static constexpr float NEGV = -1e9f;
static constexpr float SC   = 0.05f;   // 1/SCALE = 1/20

// Fragment-major layouts (written by proj):
//  Q,K:  [bh][tile16 t][ds 0..5][slot 0..63][e 0..7]   slot=(g*16+c) <-> row=t*16+c, col=ds*32+g*8+e
//  V:    [bh][kb64][cid 0..23][slot][e]  cid=dt*2+ks  <-> d=dt*16+c,  k=kb64*64+ks*32+g*8+e
//  P:    [bh][poff(qt)+kc][slot][e]  A-frag: slot=(g*16+c) <-> q=qt*16+c, k=kc*32+g*8+e
//        triangular packed: kc = 0..qt>>1 ; 4160 chunks/bh

__device__ __forceinline__ int poff(int qt){
    int m = qt>>1;
    return qt + m*(m-1) + ((qt&1) ? m : 0);
}

__device__ __forceinline__ void gload16(const void* g, void* l){
    __builtin_amdgcn_global_load_lds(
        (const __attribute__((address_space(1))) void*)g,
        (__attribute__((address_space(3))) void*)l, 16, 0, 0);
}

// ---------------- fused f32 -> f16 convert of x and the 3 weight matrices ----------------
__global__ __launch_bounds__(256) void cvtall_kernel(
    const float* __restrict__ x,
    const float* __restrict__ Wq, const float* __restrict__ Wk, const float* __restrict__ Wv,
    f16* __restrict__ xb, f16* __restrict__ Wb)
{
    int idx = blockIdx.x*256 + threadIdx.x;
    const float* src; f16* dst; int i;
    if (idx < 1572864){                       // x: 8192*768/4 float4s
        src = x; dst = xb; i = idx*4;
    } else {
        int widx = idx - 1572864;             // 0..442367
        int which = widx / 147456;
        int r = widx - which*147456;
        src = (which==0) ? Wq : (which==1 ? Wk : Wv);
        dst = Wb + (size_t)which*589824;
        i = r*4;
    }
    float4 v = *reinterpret_cast<const float4*>(src + i);
    f16x4 o = { (f16)v.x, (f16)v.y, (f16)v.z, (f16)v.w };
    *reinterpret_cast<f16x4*>(dst + i) = o;
}

// ---------------- QKV projection ----------------
// XCD-chunked block swizzle (1152 = 8*144, bijective); 2-phase double-buffered staging;
// LDS-staged vectorized epilogue for Q/K.
__global__ __launch_bounds__(256) void proj_kernel(
    const f16* __restrict__ xb, const f16* __restrict__ Wb,
    const float* __restrict__ bq, const float* __restrict__ bk, const float* __restrict__ bv,
    f16* __restrict__ Qb, f16* __restrict__ Kb, f16* __restrict__ Vt)
{
    __shared__ f16 shmem[16384];   // 32 KB: As dbuf 16K f16? -> As:0/4096, Bs:8192/12288; epilogue reuse
    // bijective XCD-chunk swizzle
    const int lin = (blockIdx.z*64 + blockIdx.y)*6 + blockIdx.x;   // 0..1151
    const int idx = (lin & 7)*144 + (lin >> 3);
    const int nx = idx % 6;
    const int t2 = idx / 6;
    const int ny = t2 & 63;
    const int z  = t2 >> 6;

    const f16*   Wz   = Wb + (size_t)z*768*768;
    const float* bias = (z==0) ? bq : (z==1 ? bk : bv);
    f16*         out  = (z==0) ? Qb : (z==1 ? Kb : Vt);
    const int row0 = ny*128, n0 = nx*128;
    const int tid = threadIdx.x, w = tid>>6, l = tid&63;
    const int wm = w>>1, wn = w&1, c = l&15, g = l>>4;
    f32x4 zero = {0.f,0.f,0.f,0.f};
    f32x4 acc[4][4];
    for (int i=0;i<4;i++) for (int j=0;j<4;j++) acc[i][j] = zero;

    const f16* ag = xb + (size_t)(row0 + w*32 + (l>>2))*768 + (l&3)*8;
    const f16* bg = Wz + (size_t)(n0   + w*32 + (l>>2))*768 + (l&3)*8;

    auto stage = [&](int buf, int k0){
        f16* As = shmem + buf*4096;
        f16* Bs = shmem + 8192 + buf*4096;
        gload16(ag + k0,          &As[w*1024      ]);
        gload16(ag + k0 + 16*768, &As[w*1024 + 512]);
        gload16(bg + k0,          &Bs[w*1024      ]);
        gload16(bg + k0 + 16*768, &Bs[w*1024 + 512]);
    };

    stage(0, 0);
    __syncthreads();
    for (int it=0; it<24; it++){
        int cur = it&1;
        if (it < 23) stage(cur^1, (it+1)*32);
        const f16* As = shmem + cur*4096;
        const f16* Bs = shmem + 8192 + cur*4096;
        f16x8 af[4], bf[4];
        for (int mt=0; mt<4; mt++)
            af[mt] = *reinterpret_cast<const f16x8*>(&As[(wm*64 + mt*16 + c)*32 + g*8]);
        for (int nt=0; nt<4; nt++)
            bf[nt] = *reinterpret_cast<const f16x8*>(&Bs[(wn*64 + nt*16 + c)*32 + g*8]);
        for (int mt=0; mt<4; mt++)
            for (int nt=0; nt<4; nt++)
                acc[mt][nt] = MFMA16(af[mt], bf[nt], acc[mt][nt]);
        __syncthreads();
    }

    if (z < 2){
        // stage the 128x128 f16 output tile in LDS in frag-major image, then linear copy-out
        for (int nt=0; nt<4; nt++){
            int nl = wn*64 + nt*16 + c;
            float bv_ = bias[n0 + nl];
            for (int mt=0; mt<4; mt++){
                for (int r=0;r<4;r++){
                    int ml = wm*64 + mt*16 + g*4 + r;
                    int li = ((ml>>4)<<11) + ((nl>>5)<<9) + (((nl>>3)&3)<<7) + ((ml&15)<<3) + (nl&7);
                    shmem[li] = (f16)(acc[mt][nt][r] + bv_);
                }
            }
        }
        __syncthreads();
        const int bi = row0>>11, st0 = (row0&2047)>>4, bh0 = bi*4;
        for (int cc=0; cc<8; cc++){
            int chunk = cc*4 + w;           // 0..31
            int tile = chunk>>2, seg = chunk&3;
            f16x8 vv = *reinterpret_cast<const f16x8*>(&shmem[chunk*512 + l*8]);
            int dglob = n0 + seg*32;
            int h  = dglob/192;
            int ds = (dglob - h*192)>>5;
            *reinterpret_cast<f16x8*>(
                out + ((size_t)((bh0 + h)*128 + st0 + tile)*6 + ds)*512 + l*8) = vv;
        }
    } else {
        for (int nt=0; nt<4; nt++){
            int nb = n0 + wn*64 + nt*16;
            int h  = nb/192;
            int d  = (nb - h*192) + c;
            float bv_ = bias[nb + c];
            for (int mt=0; mt<4; mt++){
                int mb = row0 + wm*64 + mt*16 + g*4;
                int bi = mb>>11, s0 = mb&2047;
                int bh = bi*4 + h;
                int dt = d>>4, cV = d&15;
                int kb64 = s0>>6, ks = (s0>>5)&1, gk = (s0>>3)&3, e0 = s0&7;
                f16x4 pk = { (f16)(acc[mt][nt][0] + bv_), (f16)(acc[mt][nt][1] + bv_),
                             (f16)(acc[mt][nt][2] + bv_), (f16)(acc[mt][nt][3] + bv_) };
                *reinterpret_cast<f16x4*>(
                    &out[ ((size_t)(bh*32 + kb64)*24 + dt*2 + ks)*512 + (gk*16 + cV)*8 + e0 ]) = pk;
            }
        }
    }
}

// pass 1: P = exp(S*SC) (masked, causal-zeroed), stored A-frag packed; L[k] += col sums.
// grid (qb=16, ch=4, bh=16), 512 thr. k-step 64, double-buffered.
__global__ __launch_bounds__(512,4) void qkexp_kernel(
    const f16* __restrict__ Qb, const f16* __restrict__ Kb,
    const unsigned char* __restrict__ am,
    float* __restrict__ L, f16* __restrict__ Pg)
{
    __shared__ f16 Ks[2][24*512];
    __shared__ f16 Pl[8][16*32];
    const int bh = blockIdx.z, b = bh>>2;
    const int qb = blockIdx.x;
    const int ch = blockIdx.y;
    if (qb < 4*ch) return;
    const int tid = threadIdx.x, w = tid>>6, l = tid&63;
    const int c = l&15, g = l>>4;
    const int qt = qb*8 + w, qw = qt*16;
    const f16* Kfm = Kb + (size_t)bh*128*6*512;
    char* Pb = (char*)(&Pl[w][0]);
    f16* pw = Pg + ((size_t)bh*4160 + poff(qt))*512 + l*8;
    float* Lb = L + bh*2048;

    f16x8 qf[6];
    {
        const f16* qbase = Qb + ((size_t)(bh*128 + qt)*6)*512 + l*8;
        for (int ds=0; ds<6; ds++) qf[ds] = *reinterpret_cast<const f16x8*>(qbase + ds*512);
    }
    bool pm[4];
    for (int r=0;r<4;r++) pm[r] = am[b*2048 + qw + g*4 + r] != 0;

    f32x4 zero = {0.f,0.f,0.f,0.f};
    const int k00  = ch*512;
    const int kend = min(ch*512 + 512, qb*128 + 128);
    const int nt   = (kend - k00) >> 6;
    const int cid  = w*3;

    auto stage = [&](int buf, int k0){
        for (int i=0;i<3;i++){
            int ci = cid + i;
            int tl = ci/6, ds = ci - tl*6;
            gload16(Kfm + ((size_t)((k0>>4) + tl)*6 + ds)*512 + l*8, &Ks[buf][ci*512]);
        }
    };

    stage(0, k00);
    __syncthreads();
    for (int it=0; it<nt; it++){
        int cur = it&1;
        int k0  = k00 + it*64;
        if (it+1 < nt) stage(cur^1, k0 + 64);

        for (int half=0; half<2; half++){
            int kh = k0 + half*32;
            if (kh <= qw + 15){
                float cs[2];
                for (int kt2=0; kt2<2; kt2++){
                    int ktile = half*2 + kt2;
                    int kk = k0 + ktile*16;
                    f32x4 sacc = zero;
                    for (int ds=0; ds<6; ds++){
                        f16x8 kfr = *reinterpret_cast<const f16x8*>(&Ks[cur][(ktile*6+ds)*512 + l*8]);
                        sacc = MFMA16(qf[ds], kfr, sacc);
                    }
                    float csl = 0.f;
                    for (int r=0;r<4;r++){
                        int q = qw + g*4 + r;
                        float v = sacc[r]*SC;
                        if (pm[r]) v = NEGV;
                        float p = __expf(v);
                        if (kk + c > q) p = 0.f;
                        csl += p;
                        int row = g*4 + r;
                        int byo = (row*64 + (kt2*16 + c)*2) ^ ((row&3)<<4);
                        *reinterpret_cast<f16*>(Pb + byo) = (f16)p;
                    }
                    csl += __shfl_xor(csl, 16);
                    csl += __shfl_xor(csl, 32);
                    cs[kt2] = csl;
                }
                {
                    int byo = (c*64 + g*16) ^ ((c&3)<<4);
                    f16x8 pa = *reinterpret_cast<const f16x8*>(Pb + byo);
                    *reinterpret_cast<f16x8*>(pw + (size_t)(kh>>5)*512) = pa;
                }
                if (l < 32){
                    float csv = (l < 16) ? cs[0] : cs[1];
                    int kcol = kh + ((l < 16) ? 0 : 16) + (l & 15);
                    atomicAdd(&Lb[kcol], csv);
                }
            }
        }
        __syncthreads();
    }
}

// pass 2: x1 = (P * 1/L[k]) @ V. Barrier-free, LDS-free; scalev folded in (P-side iL scaling).
// Per-wave task (qt, d-half, bh), pair-balanced qt, coalesced global reads, plain f32 stores.
__global__ __launch_bounds__(512) void pv_kernel(
    const f16* __restrict__ Pg, const f16* __restrict__ Vt,
    const float* __restrict__ L, float* __restrict__ x1)
{
    const int t  = blockIdx.x*8 + (threadIdx.x>>6);
    const int l  = threadIdx.x&63, c = l&15, g = l>>4;
    const int bh = t >> 8;
    const int r8 = t & 255;
    const int dh = r8 & 1;                 // d-half: dt = dh*6 + 0..5
    const int j  = r8 >> 1;
    const int qt = (j&1) ? (127 - (j>>1)) : (j>>1);
    const int b = bh>>2, h = bh&3;
    const int qw = qt*16;
    const f16* Vfm = Vt + (size_t)bh*32*24*512;
    const f16* pp  = Pg + ((size_t)bh*4160 + poff(qt))*512 + l*8;
    const float* Lb = L + bh*2048 + g*8;   // lane's 8 k-slots base (per 32-chunk offset added)
    const int nc = (qt>>1) + 1;            // 32-wide k-chunks

    auto scale8 = [&](f16x8 p, int koff)->f16x8{
        const float* Lp = Lb + koff;
        f32x4 a  = *reinterpret_cast<const f32x4*>(Lp);
        f32x4 b2 = *reinterpret_cast<const f32x4*>(Lp + 4);
        f16x8 o;
        o[0] = (f16)((float)p[0] * __builtin_amdgcn_rcpf(fmaxf(a[0],  1e-30f)));
        o[1] = (f16)((float)p[1] * __builtin_amdgcn_rcpf(fmaxf(a[1],  1e-30f)));
        o[2] = (f16)((float)p[2] * __builtin_amdgcn_rcpf(fmaxf(a[2],  1e-30f)));
        o[3] = (f16)((float)p[3] * __builtin_amdgcn_rcpf(fmaxf(a[3],  1e-30f)));
        o[4] = (f16)((float)p[4] * __builtin_amdgcn_rcpf(fmaxf(b2[0], 1e-30f)));
        o[5] = (f16)((float)p[5] * __builtin_amdgcn_rcpf(fmaxf(b2[1], 1e-30f)));
        o[6] = (f16)((float)p[6] * __builtin_amdgcn_rcpf(fmaxf(b2[2], 1e-30f)));
        o[7] = (f16)((float)p[7] * __builtin_amdgcn_rcpf(fmaxf(b2[3], 1e-30f)));
        return o;
    };

    f32x4 zero = {0.f,0.f,0.f,0.f};
    f32x4 acc[6];
    for (int i=0;i<6;i++) acc[i] = zero;

    int kc = 0;
    for (; kc+1 < nc; kc += 2){
        const f16* pap = pp + (size_t)kc*512;
        f16x8 paA = scale8(*reinterpret_cast<const f16x8*>(pap),       kc*32);
        f16x8 paB = scale8(*reinterpret_cast<const f16x8*>(pap + 512), kc*32 + 32);
        const f16* vb = Vfm + ((size_t)(kc>>1)*24 + dh*12)*512 + l*8;
        f16x8 vA[6], vB[6];
        #pragma unroll
        for (int d2=0; d2<6; d2++){
            vA[d2] = *reinterpret_cast<const f16x8*>(vb + d2*1024);
            vB[d2] = *reinterpret_cast<const f16x8*>(vb + d2*1024 + 512);
        }
        #pragma unroll
        for (int d2=0; d2<6; d2++) acc[d2] = MFMA16(paA, vA[d2], acc[d2]);
        #pragma unroll
        for (int d2=0; d2<6; d2++) acc[d2] = MFMA16(paB, vB[d2], acc[d2]);
    }
    if (kc < nc){
        f16x8 paA = scale8(*reinterpret_cast<const f16x8*>(pp + (size_t)kc*512), kc*32);
        const f16* vb = Vfm + ((size_t)(kc>>1)*24 + dh*12)*512 + l*8;
        #pragma unroll
        for (int d2=0; d2<6; d2++){
            f16x8 vA = *reinterpret_cast<const f16x8*>(vb + d2*1024);
            acc[d2] = MFMA16(paA, vA, acc[d2]);
        }
    }

    for (int d2=0; d2<6; d2++){
        int d = h*192 + (dh*6 + d2)*16 + c;
        for (int r=0;r<4;r++){
            int q = qw + g*4 + r;
            x1[(size_t)(b*2048 + q)*768 + d] = acc[d2][r];
        }
    }
}

// ---------------- residual + layernorm ----------------
__global__ __launch_bounds__(256) void ln_kernel(
    const float* __restrict__ x, const float* __restrict__ x1,
    const float* __restrict__ gamma, const float* __restrict__ beta,
    float* __restrict__ out)
{
    const int r = blockIdx.x, t = threadIdx.x;
    const float* xr = x  + (size_t)r*768;
    const float* yr = x1 + (size_t)r*768;
    float v[3]; float s1 = 0.f, s2 = 0.f;
    for (int i=0;i<3;i++){ int j = t + i*256; float y = xr[j] + yr[j]; v[i]=y; s1+=y; s2+=y*y; }
    for (int o=32;o>=1;o>>=1){ s1 += __shfl_xor(s1,o); s2 += __shfl_xor(s2,o); }
    __shared__ float a1[4], a2[4];
    if ((t&63)==0){ a1[t>>6]=s1; a2[t>>6]=s2; }
    __syncthreads();
    s1 = a1[0]+a1[1]+a1[2]+a1[3];
    s2 = a2[0]+a2[1]+a2[2]+a2[3];
    float mu  = s1*(1.f/768.f);
    float var = s2*(1.f/768.f) - mu*mu;
    float rs  = rsqrtf(var + 1e-5f);
    for (int i=0;i<3;i++){
        int j = t + i*256;
        out[(size_t)r*768 + j] = (v[i]-mu)*rs*gamma[j] + beta[j];
    }
}

extern "C" void kernel_launch(void* const* d_in, const int* in_sizes, int n_in,
                              void* d_out, int out_size, void* d_ws, size_t ws_size,
                              hipStream_t stream)
{
    const float* x     = (const float*)d_in[0];
    const unsigned char* am = (const unsigned char*)d_in[1];
    const float* Wq    = (const float*)d_in[2];
    const float* bq    = (const float*)d_in[3];
    const float* Wk    = (const float*)d_in[4];
    const float* bk    = (const float*)d_in[5];
    const float* Wv    = (const float*)d_in[6];
    const float* bv    = (const float*)d_in[7];
    const float* gamma = (const float*)d_in[8];
    const float* beta  = (const float*)d_in[9];
    float* out = (float*)d_out;

    f16* xb  = (f16*)d_ws;
    f16* Wb  = xb + (size_t)8192*768;
    f16* Qb  = Wb + (size_t)3*768*768;
    f16* Kb  = Qb + (size_t)16*2048*192;
    f16* Vt  = Kb + (size_t)16*2048*192;
    f16* Pg  = Vt + (size_t)16*2048*192;       // triangular-packed P (68 MB)
    float* L  = (float*)xb;                    // aliases xb (dead after proj)
    float* x1 = (float*)Qb;                    // aliases Qb+Kb (dead after qkexp)

    cvtall_kernel<<<7872, 256, 0, stream>>>(x, Wq, Wk, Wv, xb, Wb);
    proj_kernel<<<dim3(6,64,3), 256, 0, stream>>>(xb, Wb, bq, bk, bv, Qb, Kb, Vt);
    hipMemsetAsync(L, 0, 16*2048*sizeof(float), stream);
    qkexp_kernel<<<dim3(16,4,16), 512, 0, stream>>>(Qb, Kb, am, L, Pg);
    pv_kernel<<<512, 512, 0, stream>>>(Pg, Vt, L, x1);
    ln_kernel<<<8192, 256, 0, stream>>>(x, x1, gamma, beta, out);
}